// Round 1
// baseline (538.184 us; speedup 1.0000x reference)
//
#include <hip/hip_runtime.h>
#include <math.h>

constexpr int B = 16, S = 2048, D = 64;
constexpr int TK = 64;          // fallback: keys per tile
constexpr int NT = S / TK;      // 32
constexpr float SCALE = 0.125f; // 1/sqrt(64)

typedef __attribute__((ext_vector_type(8))) short bf16x8;
typedef __attribute__((ext_vector_type(4))) float f32x4;
typedef __attribute__((ext_vector_type(16))) float f32x16;

__device__ __forceinline__ unsigned short f2bf(float x) {
    union { float f; unsigned u; } c; c.f = x;
    return (unsigned short)((c.u + 0x7fff + ((c.u >> 16) & 1)) >> 16);  // RNE
}
__device__ __forceinline__ float bf2f(unsigned short h) {
    union { unsigned u; float f; } c; c.u = ((unsigned)h) << 16; return c.f;
}
__device__ __forceinline__ unsigned pk2(float a, float b) {
    return (unsigned)f2bf(a) | ((unsigned)f2bf(b) << 16);
}
__device__ __forceinline__ int rowof(int h, int r) { return (r & 3) + 8 * (r >> 2) + 4 * h; }

// ============ pre-pass: Q,K -> bf16 [b][s][d]; V -> bf16 transposed [b][d][s] ============
__global__ __launch_bounds__(256)
void preconv(const float* __restrict__ q, const float* __restrict__ k,
             const float* __restrict__ v, unsigned short* __restrict__ Qb,
             unsigned short* __restrict__ Kb, unsigned short* __restrict__ Vtb)
{
    __shared__ unsigned short vt[64 * 72];  // [d][s-local], stride 72 (16B-aligned rows)
    const int b = blockIdx.x >> 5, s0 = (blockIdx.x & 31) * 64;
    const int t = threadIdx.x;

    const float4* qs = (const float4*)(q + ((size_t)b * S + s0) * D);
    const float4* ks = (const float4*)(k + ((size_t)b * S + s0) * D);
    const float4* vs = (const float4*)(v + ((size_t)b * S + s0) * D);
    unsigned* Qd = (unsigned*)(Qb + ((size_t)b * S + s0) * D);
    unsigned* Kd = (unsigned*)(Kb + ((size_t)b * S + s0) * D);

    #pragma unroll
    for (int i = 0; i < 4; ++i) {
        int f4 = t + 256 * i;
        float4 x = qs[f4];
        Qd[f4 * 2] = pk2(x.x, x.y); Qd[f4 * 2 + 1] = pk2(x.z, x.w);
        float4 y = ks[f4];
        Kd[f4 * 2] = pk2(y.x, y.y); Kd[f4 * 2 + 1] = pk2(y.z, y.w);
        float4 z = vs[f4];
        int r = f4 >> 4, cc = (f4 & 15) * 4;      // r = s-local, cc = d
        vt[(cc + 0) * 72 + r] = f2bf(z.x);
        vt[(cc + 1) * 72 + r] = f2bf(z.y);
        vt[(cc + 2) * 72 + r] = f2bf(z.z);
        vt[(cc + 3) * 72 + r] = f2bf(z.w);
    }
    __syncthreads();
    #pragma unroll
    for (int i = 0; i < 2; ++i) {
        int ch = t + 256 * i;                     // 512 chunks of 16B
        int d = ch >> 3, o = ch & 7;
        int4 val = *(const int4*)&vt[d * 72 + o * 8];
        *(int4*)(Vtb + ((size_t)(b * 64 + d)) * S + s0 + o * 8) = val;
    }
}

// ============ v4: wave-independent, zero inner-loop barriers ============
// Per block: 32 q-rows. 4 waves each own a 512-key quarter (16 tiles of 32 keys).
// K and V^T B-fragments load straight from global (L2/LLC-resident: 512 KB/batch).
// LDS: wave-private P tile (transpose for coalesced attn store + PV A-operand),
// aliased at the end by the O-combine buffer. 4 barriers per kernel total.
constexpr int TQ2  = 32;        // q rows per block
constexpr int KW2  = S / 4;     // 512 keys per wave
constexpr int TK2  = 32;        // keys per inner tile
constexpr int NT2  = KW2 / TK2; // 16
constexpr int PSTR = 40;        // Ps stride (shorts): 80 B rows -> h-halves on disjoint bank sets

__global__ __launch_bounds__(256, 4)
void sdpa_v4(const unsigned short* __restrict__ Qb, const unsigned short* __restrict__ Kb,
             const unsigned short* __restrict__ Vtb, const int* __restrict__ maskg,
             float* __restrict__ outg, float* __restrict__ attng)
{
    // 32 KB: during the loop, first 10 KB = 4 wave-private Ps tiles; after the
    // final barrier the whole buffer becomes the 4x(32x64) O-combine scratch.
    __shared__ __align__(16) float smem[4 * TQ2 * D];
    __shared__ float rsum[4][TQ2];
    __shared__ float tot[TQ2];

    const int t = threadIdx.x;
    const int w = t >> 6, lane = t & 63, m = lane & 31, h = lane >> 5;
    int bid = (int)blockIdx.x;
    bid = (bid & 7) * 128 + (bid >> 3);       // XCD swizzle: ~2 batches per XCD L2 (1024 % 8 == 0)
    const int b  = bid >> 6;
    const int q0 = (bid & 63) * TQ2;
    const int k0 = w * KW2;

    const unsigned short* Kbase = Kb  + (size_t)b * S * D;
    const unsigned short* Vbase = Vtb + (size_t)b * D * S;
    const int* mbase = maskg + b * S;
    short* Psw = reinterpret_cast<short*>(smem) + w * (TQ2 * PSTR);

    // Q fragments (rows q0+m), once
    bf16x8 aq[4];
    {
        const unsigned short* qrow = Qb + ((size_t)(b * S + q0 + m)) * D + h * 8;
        #pragma unroll
        for (int s = 0; s < 4; ++s) aq[s] = *(const bf16x8*)(qrow + s * 16);
    }

    // ---------------- pass 1: unnormalized row sums over this wave's quarter ----------------
    float rs[16];
    #pragma unroll
    for (int r = 0; r < 16; ++r) rs[r] = 0.f;

    #pragma unroll 2
    for (int it = 0; it < NT2; ++it) {
        const int gk = k0 + it * TK2;
        const int mk = mbase[gk + m];
        const unsigned short* krow = Kbase + (size_t)(gk + m) * D + h * 8;
        f32x16 c;
        #pragma unroll
        for (int i = 0; i < 16; ++i) c[i] = 0.f;
        #pragma unroll
        for (int s = 0; s < 4; ++s) {
            bf16x8 bk = *(const bf16x8*)(krow + s * 16);
            c = __builtin_amdgcn_mfma_f32_32x32x16_bf16(aq[s], bk, c, 0, 0, 0);
        }
        if (mk == 0) {
            #pragma unroll
            for (int r = 0; r < 16; ++r) rs[r] += __expf(c[r] * SCALE);
        }
    }
    #pragma unroll
    for (int off = 1; off < 32; off <<= 1)
        #pragma unroll
        for (int r = 0; r < 16; ++r) rs[r] += __shfl_xor(rs[r], off, 64);
    if (m == 0) {
        #pragma unroll
        for (int r = 0; r < 16; ++r) rsum[w][rowof(h, r)] = rs[r];
    }
    __syncthreads();
    if (t < TQ2) tot[t] = rsum[0][t] + rsum[1][t] + rsum[2][t] + rsum[3][t];
    __syncthreads();
    const float tm = tot[m];
    const float rli_m = tm > 0.f ? 1.f / tm : 0.f;   // scale for attn rows (row = m at store time)

    // ---------------- pass 2: recompute scores, attn store + PV (no barriers) ----------------
    f32x16 o0, o1;
    #pragma unroll
    for (int i = 0; i < 16; ++i) { o0[i] = 0.f; o1[i] = 0.f; }

    #pragma unroll 2
    for (int it = 0; it < NT2; ++it) {
        const int gk = k0 + it * TK2;
        const int mk = mbase[gk + m];
        const unsigned short* krow = Kbase + (size_t)(gk + m) * D + h * 8;
        f32x16 c;
        #pragma unroll
        for (int i = 0; i < 16; ++i) c[i] = 0.f;
        #pragma unroll
        for (int s = 0; s < 4; ++s) {
            bf16x8 bk = *(const bf16x8*)(krow + s * 16);
            c = __builtin_amdgcn_mfma_f32_32x32x16_bf16(aq[s], bk, c, 0, 0, 0);
        }
        // wave-private P tile, UNNORMALIZED exp in bf16 (normalize at store / epilogue)
        if (mk == 0) {
            #pragma unroll
            for (int r = 0; r < 16; ++r)
                Psw[rowof(h, r) * PSTR + m] = (short)f2bf(__expf(c[r] * SCALE));
        } else {
            #pragma unroll
            for (int r = 0; r < 16; ++r) Psw[rowof(h, r) * PSTR + m] = 0;
        }
        // (same-wave LDS write->read ordering handled by compiler lgkmcnt; no barrier needed)

        // PV: A = P rows m, B = V^T rows d (d = m / 32+m), direct from global
        #pragma unroll
        for (int kk = 0; kk < 2; ++kk) {
            bf16x8 ap  = *(const bf16x8*)&Psw[m * PSTR + kk * 16 + h * 8];
            bf16x8 bv0 = *(const bf16x8*)(Vbase + (size_t)m * S + gk + kk * 16 + h * 8);
            bf16x8 bv1 = *(const bf16x8*)(Vbase + (size_t)(32 + m) * S + gk + kk * 16 + h * 8);
            o0 = __builtin_amdgcn_mfma_f32_32x32x16_bf16(ap, bv0, o0, 0, 0, 0);
            o1 = __builtin_amdgcn_mfma_f32_32x32x16_bf16(ap, bv1, o1, 0, 0, 0);
        }

        // attn store: lane -> row m, cols gk + h*16 .. +15; scaled; nontemporal
        {
            const short* pr = &Psw[m * PSTR + h * 16];
            bf16x8 p0 = *(const bf16x8*)pr;
            bf16x8 p1 = *(const bf16x8*)(pr + 8);
            float* ab = attng + ((size_t)(b * S + q0 + m)) * S + gk + h * 16;
            f32x4 f0 = { bf2f((unsigned short)p0[0]) * rli_m, bf2f((unsigned short)p0[1]) * rli_m,
                         bf2f((unsigned short)p0[2]) * rli_m, bf2f((unsigned short)p0[3]) * rli_m };
            f32x4 f1 = { bf2f((unsigned short)p0[4]) * rli_m, bf2f((unsigned short)p0[5]) * rli_m,
                         bf2f((unsigned short)p0[6]) * rli_m, bf2f((unsigned short)p0[7]) * rli_m };
            f32x4 f2 = { bf2f((unsigned short)p1[0]) * rli_m, bf2f((unsigned short)p1[1]) * rli_m,
                         bf2f((unsigned short)p1[2]) * rli_m, bf2f((unsigned short)p1[3]) * rli_m };
            f32x4 f3 = { bf2f((unsigned short)p1[4]) * rli_m, bf2f((unsigned short)p1[5]) * rli_m,
                         bf2f((unsigned short)p1[6]) * rli_m, bf2f((unsigned short)p1[7]) * rli_m };
            __builtin_nontemporal_store(f0, (f32x4*)ab);
            __builtin_nontemporal_store(f1, (f32x4*)(ab + 4));
            __builtin_nontemporal_store(f2, (f32x4*)(ab + 8));
            __builtin_nontemporal_store(f3, (f32x4*)(ab + 12));
        }
    }

    // ---------------- combine partial O across the 4 waves ----------------
    __syncthreads();                    // all waves done with Psw (aliased below)
    {
        float* Ocw = smem + w * (TQ2 * D);
        #pragma unroll
        for (int r = 0; r < 16; ++r) {
            const int row = rowof(h, r);
            Ocw[row * D + m]      = o0[r];
            Ocw[row * D + 32 + m] = o1[r];
        }
    }
    __syncthreads();
    {
        float* ob = outg + ((size_t)(b * S + q0)) * D;
        #pragma unroll
        for (int i = 0; i < 2; ++i) {
            const int i4 = t * 2 + i;   // 0..511 float4 slots over 32x64
            f32x4 a0 = *(const f32x4*)&smem[0 * TQ2 * D + i4 * 4];
            f32x4 a1 = *(const f32x4*)&smem[1 * TQ2 * D + i4 * 4];
            f32x4 a2 = *(const f32x4*)&smem[2 * TQ2 * D + i4 * 4];
            f32x4 a3 = *(const f32x4*)&smem[3 * TQ2 * D + i4 * 4];
            const float tr = tot[i4 >> 4];
            const float sc = tr > 0.f ? 1.f / tr : 0.f;
            f32x4 sum = (a0 + a1 + a2 + a3) * sc;
            *(f32x4*)&ob[i4 * 4] = sum;
        }
    }
}

// ============ fallback (R2 kernel) if workspace is too small ============
__global__ __launch_bounds__(256)
void sdpa_fb(const float* __restrict__ qg, const float* __restrict__ kg,
             const float* __restrict__ vg, const int* __restrict__ maskg,
             float* __restrict__ outg, float* __restrict__ attng)
{
    constexpr int FSTR = 72;
    __shared__ __align__(16) short Qs[128 * FSTR];
    __shared__ __align__(16) short KsF[64 * FSTR];
    __shared__ __align__(16) short VtF[64 * FSTR];
    __shared__ __align__(16) short PsF[4 * 32 * FSTR];
    __shared__ float mflag[64];

    const int t = threadIdx.x;
    const int w = t >> 6, lane = t & 63, m = lane & 31, half = lane >> 5;
    const int b = blockIdx.x >> 4;
    const int q0 = (blockIdx.x & 15) * 128;

    {
        const float4* src = (const float4*)(qg + ((size_t)b * S + q0) * D);
        #pragma unroll
        for (int i = 0; i < 8; ++i) {
            int f4 = t + i * 256;
            float4 v = src[f4];
            unsigned* dst = (unsigned*)&Qs[(f4 >> 4) * FSTR + (f4 & 15) * 4];
            dst[0] = pk2(v.x, v.y); dst[1] = pk2(v.z, v.w);
        }
    }
    __syncthreads();
    bf16x8 aq[4];
    #pragma unroll
    for (int s = 0; s < 4; ++s)
        aq[s] = *(const bf16x8*)&Qs[(w * 32 + m) * FSTR + s * 16 + half * 8];

    auto stageK = [&](int gk) {
        const float4* src = (const float4*)(kg + ((size_t)b * S + gk) * D);
        #pragma unroll
        for (int i = 0; i < 4; ++i) {
            int f4 = t + i * 256;
            float4 v = src[f4];
            unsigned* dst = (unsigned*)&KsF[(f4 >> 4) * FSTR + (f4 & 15) * 4];
            dst[0] = pk2(v.x, v.y); dst[1] = pk2(v.z, v.w);
        }
        if (t < 64) mflag[t] = maskg[b * S + gk + t] ? 1.0f : 0.0f;
    };
    auto stageV = [&](int gk) {
        const float4* src = (const float4*)(vg + ((size_t)b * S + gk) * D);
        #pragma unroll
        for (int i = 0; i < 4; ++i) {
            int f4 = t + i * 256;
            float4 v = src[f4];
            int r = f4 >> 4, cc = (f4 & 15) * 4;
            VtF[(cc + 0) * FSTR + r] = (short)f2bf(v.x);
            VtF[(cc + 1) * FSTR + r] = (short)f2bf(v.y);
            VtF[(cc + 2) * FSTR + r] = (short)f2bf(v.z);
            VtF[(cc + 3) * FSTR + r] = (short)f2bf(v.w);
        }
    };
    auto scoresF = [&](f32x16& c0, f32x16& c1) {
        #pragma unroll
        for (int i = 0; i < 16; ++i) { c0[i] = 0.f; c1[i] = 0.f; }
        #pragma unroll
        for (int s = 0; s < 4; ++s) {
            bf16x8 b0 = *(const bf16x8*)&KsF[m * FSTR + s * 16 + half * 8];
            bf16x8 b1 = *(const bf16x8*)&KsF[(32 + m) * FSTR + s * 16 + half * 8];
            c0 = __builtin_amdgcn_mfma_f32_32x32x16_bf16(aq[s], b0, c0, 0, 0, 0);
            c1 = __builtin_amdgcn_mfma_f32_32x32x16_bf16(aq[s], b1, c1, 0, 0, 0);
        }
    };

    float rs[16];
    #pragma unroll
    for (int r = 0; r < 16; ++r) rs[r] = 0.f;
    for (int tile = 0; tile < NT; ++tile) {
        stageK(tile * TK);
        __syncthreads();
        f32x16 c0, c1; scoresF(c0, c1);
        float mk0 = mflag[m], mk1 = mflag[32 + m];
        #pragma unroll
        for (int r = 0; r < 16; ++r) {
            float p0 = (mk0 == 0.f) ? __expf(c0[r] * SCALE) : 0.f;
            float p1 = (mk1 == 0.f) ? __expf(c1[r] * SCALE) : 0.f;
            rs[r] += p0 + p1;
        }
        __syncthreads();
    }
    #pragma unroll
    for (int off = 1; off < 32; off <<= 1)
        #pragma unroll
        for (int r = 0; r < 16; ++r) rs[r] += __shfl_xor(rs[r], off, 64);
    float rli[16];
    #pragma unroll
    for (int r = 0; r < 16; ++r) rli[r] = rs[r] > 0.f ? 1.f / rs[r] : 0.f;

    f32x16 o0, o1;
    #pragma unroll
    for (int i = 0; i < 16; ++i) { o0[i] = 0.f; o1[i] = 0.f; }
    short* Pw = &PsF[w * 32 * FSTR];
    float* abase = attng + ((size_t)(b * S + q0 + w * 32)) * S;

    for (int tile = 0; tile < NT; ++tile) {
        const int gk = tile * TK;
        stageK(gk); stageV(gk);
        __syncthreads();
        f32x16 c0, c1; scoresF(c0, c1);
        float mk0 = mflag[m], mk1 = mflag[32 + m];
        #pragma unroll
        for (int r = 0; r < 16; ++r) {
            int row = rowof(half, r);
            float p0 = (mk0 == 0.f) ? __expf(c0[r] * SCALE) * rli[r] : 0.f;
            float p1 = (mk1 == 0.f) ? __expf(c1[r] * SCALE) * rli[r] : 0.f;
            Pw[row * FSTR + m]      = (short)f2bf(p0);
            Pw[row * FSTR + 32 + m] = (short)f2bf(p1);
        }
        #pragma unroll
        for (int i = 0; i < 16; ++i) {
            int row = i * 2 + half;
            unsigned u = *(const unsigned*)&Pw[row * FSTR + 2 * m];
            float2 val = make_float2(bf2f((unsigned short)(u & 0xffff)),
                                     bf2f((unsigned short)(u >> 16)));
            *(float2*)&abase[(size_t)row * S + gk + 2 * m] = val;
        }
        #pragma unroll
        for (int kk = 0; kk < 4; ++kk) {
            bf16x8 ap  = *(const bf16x8*)&Pw[m * FSTR + kk * 16 + half * 8];
            bf16x8 bv0 = *(const bf16x8*)&VtF[m * FSTR + kk * 16 + half * 8];
            bf16x8 bv1 = *(const bf16x8*)&VtF[(32 + m) * FSTR + kk * 16 + half * 8];
            o0 = __builtin_amdgcn_mfma_f32_32x32x16_bf16(ap, bv0, o0, 0, 0, 0);
            o1 = __builtin_amdgcn_mfma_f32_32x32x16_bf16(ap, bv1, o1, 0, 0, 0);
        }
        __syncthreads();
    }
    float* obase = outg + ((size_t)(b * S + q0 + w * 32)) * D;
    #pragma unroll
    for (int r = 0; r < 16; ++r) {
        int row = rowof(half, r);
        obase[row * D + m]      = o0[r];
        obase[row * D + 32 + m] = o1[r];
    }
}

extern "C" void kernel_launch(void* const* d_in, const int* in_sizes, int n_in,
                              void* d_out, int out_size, void* d_ws, size_t ws_size,
                              hipStream_t stream) {
    const float* q    = (const float*)d_in[0];
    const float* k    = (const float*)d_in[1];
    const float* v    = (const float*)d_in[2];
    const int*   mask = (const int*)d_in[3];

    float* out  = (float*)d_out;
    float* attn = (float*)d_out + (size_t)B * S * D;

    const size_t elems = (size_t)B * S * D;
    const size_t need  = 3 * elems * sizeof(unsigned short);

    if (ws_size >= need) {
        unsigned short* Qb  = (unsigned short*)d_ws;
        unsigned short* Kb  = Qb + elems;
        unsigned short* Vtb = Kb + elems;
        preconv<<<dim3(B * (S / 64)), dim3(256), 0, stream>>>(q, k, v, Qb, Kb, Vtb);
        sdpa_v4<<<dim3(B * (S / TQ2)), dim3(256), 0, stream>>>(Qb, Kb, Vtb, mask, out, attn);
    } else {
        sdpa_fb<<<dim3(B * (S / 128)), dim3(256), 0, stream>>>(q, k, v, mask, out, attn);
    }
}

// Round 3
// 400.779 us; speedup vs baseline: 1.3428x; 1.3428x over previous
//
#include <hip/hip_runtime.h>
#include <math.h>

constexpr int B = 16, S = 2048, D = 64;
constexpr int TK = 64;          // keys per tile
constexpr int NT = S / TK;      // 32 tiles
constexpr float SCALE = 0.125f; // 1/sqrt(64)
constexpr int STRH = 72;        // LDS stride in shorts: 36 dwords ≡ 4 mod 32 → same even bank
                                // tiling as stride 88 (8-cyc b128 floor), but 47.1 KB total LDS
                                // → 3 blocks/CU (12 waves) instead of 2.

typedef __attribute__((ext_vector_type(8))) short bf16x8;
typedef __attribute__((ext_vector_type(16))) float f32x16;

__device__ __forceinline__ unsigned short f2bf(float x) {
    union { float f; unsigned u; } c; c.f = x;
    return (unsigned short)((c.u + 0x7fff + ((c.u >> 16) & 1)) >> 16);  // RNE
}
__device__ __forceinline__ float bf2f(unsigned short h) {
    union { unsigned u; float f; } c; c.u = ((unsigned)h) << 16; return c.f;
}
__device__ __forceinline__ unsigned pk2(float a, float b) {
    return (unsigned)f2bf(a) | ((unsigned)f2bf(b) << 16);
}
__device__ __forceinline__ int rowof(int h, int r) { return (r & 3) + 8 * (r >> 2) + 4 * h; }

// ============ pre-pass: Q,K -> bf16 [b][s][d]; V -> bf16 transposed [b][d][s] ============
__global__ __launch_bounds__(256)
void preconv(const float* __restrict__ q, const float* __restrict__ k,
             const float* __restrict__ v, unsigned short* __restrict__ Qb,
             unsigned short* __restrict__ Kb, unsigned short* __restrict__ Vtb)
{
    __shared__ unsigned short vt[64 * 72];  // [d][s-local], stride 72 (16B-aligned rows)
    const int b = blockIdx.x >> 5, s0 = (blockIdx.x & 31) * 64;
    const int t = threadIdx.x;

    const float4* qs = (const float4*)(q + ((size_t)b * S + s0) * D);
    const float4* ks = (const float4*)(k + ((size_t)b * S + s0) * D);
    const float4* vs = (const float4*)(v + ((size_t)b * S + s0) * D);
    unsigned* Qd = (unsigned*)(Qb + ((size_t)b * S + s0) * D);
    unsigned* Kd = (unsigned*)(Kb + ((size_t)b * S + s0) * D);

    #pragma unroll
    for (int i = 0; i < 4; ++i) {
        int f4 = t + 256 * i;
        float4 x = qs[f4];
        Qd[f4 * 2] = pk2(x.x, x.y); Qd[f4 * 2 + 1] = pk2(x.z, x.w);
        float4 y = ks[f4];
        Kd[f4 * 2] = pk2(y.x, y.y); Kd[f4 * 2 + 1] = pk2(y.z, y.w);
        float4 z = vs[f4];
        int r = f4 >> 4, cc = (f4 & 15) * 4;      // r = s-local, cc = d
        vt[(cc + 0) * 72 + r] = f2bf(z.x);
        vt[(cc + 1) * 72 + r] = f2bf(z.y);
        vt[(cc + 2) * 72 + r] = f2bf(z.z);
        vt[(cc + 3) * 72 + r] = f2bf(z.w);
    }
    __syncthreads();
    #pragma unroll
    for (int i = 0; i < 2; ++i) {
        int ch = t + 256 * i;                     // 512 chunks of 16B
        int d = ch >> 3, o = ch & 7;
        int4 val = *(const int4*)&vt[d * 72 + o * 8];
        *(int4*)(Vtb + ((size_t)(b * 64 + d)) * S + s0 + o * 8) = val;
    }
}

// ============ main: TQ=64, grid=512, 3 blocks/CU, double-buffered staging ============
__global__ __launch_bounds__(256)
void sdpa_v5(const unsigned short* __restrict__ Qb, const unsigned short* __restrict__ Kb,
             const unsigned short* __restrict__ Vtb, const int* __restrict__ maskg,
             float* __restrict__ outg, float* __restrict__ attng)
{
    __shared__ __align__(16) short Ks[2][TK * STRH];
    __shared__ __align__(16) short Vt[2][TK * STRH];
    __shared__ __align__(16) short Ps[64 * STRH];
    __shared__ float mfl[2][TK];
    __shared__ float rsum[2][64];

    const int t = threadIdx.x;
    const int w = t >> 6, lane = t & 63, m = lane & 31, h = lane >> 5;
    const int p = w >> 1, c = w & 1;   // p: q-row pair (rows 32p..), c: col side
    int bid = (int)blockIdx.x;
    bid = (bid & 7) * 64 + (bid >> 3);    // XCD swizzle, bijective on [0,512) (512 % 8 == 0):
                                          // each XCD gets 64 consecutive work units = 2 batches
                                          // → 1 MB K+V resident in its 4 MB L2
    const int b = bid >> 5;
    const int q0 = (bid & 31) * 64;

    // Q fragments straight from global bf16 (once)
    bf16x8 aq[4];
    {
        const unsigned short* qrow = Qb + ((size_t)(b * S + q0 + 32 * p + m)) * D;
        #pragma unroll
        for (int s = 0; s < 4; ++s) aq[s] = *(const bf16x8*)(qrow + s * 16 + h * 8);
    }

    int4 kreg[2], vreg[2];
    int mreg = 0;

    auto gloadK = [&](int gk) {
        #pragma unroll
        for (int i = 0; i < 2; ++i) {
            int ch = t + 256 * i;                 // 512 chunks: row = ch>>3, off16 = ch&7
            kreg[i] = *(const int4*)(Kb + ((size_t)(b * S + gk + (ch >> 3))) * D + (ch & 7) * 8);
        }
        if (t < TK) mreg = maskg[b * S + gk + t];
    };
    auto gloadV = [&](int gk) {
        #pragma unroll
        for (int i = 0; i < 2; ++i) {
            int ch = t + 256 * i;                 // row = d, off = k-chunk
            vreg[i] = *(const int4*)(Vtb + ((size_t)(b * 64 + (ch >> 3))) * S + gk + (ch & 7) * 8);
        }
    };
    auto commitK = [&](int buf) {
        #pragma unroll
        for (int i = 0; i < 2; ++i) {
            int ch = t + 256 * i;
            *(int4*)&Ks[buf][(ch >> 3) * STRH + (ch & 7) * 8] = kreg[i];
        }
        if (t < TK) mfl[buf][t] = mreg ? 1.0f : 0.0f;
    };
    auto commitV = [&](int buf) {
        #pragma unroll
        for (int i = 0; i < 2; ++i) {
            int ch = t + 256 * i;
            *(int4*)&Vt[buf][(ch >> 3) * STRH + (ch & 7) * 8] = vreg[i];
        }
    };
    auto scores = [&](int buf, f32x16& c0) {
        #pragma unroll
        for (int i = 0; i < 16; ++i) c0[i] = 0.f;
        __builtin_amdgcn_s_setprio(1);
        #pragma unroll
        for (int s = 0; s < 4; ++s) {
            bf16x8 bk = *(const bf16x8*)&Ks[buf][(32 * c + m) * STRH + s * 16 + h * 8];
            c0 = __builtin_amdgcn_mfma_f32_32x32x16_bf16(aq[s], bk, c0, 0, 0, 0);
        }
        __builtin_amdgcn_s_setprio(0);
    };

    // ---------------- pass 1: row sums ----------------
    float rs[16];
    #pragma unroll
    for (int r = 0; r < 16; ++r) rs[r] = 0.f;

    gloadK(0);
    for (int t2 = 0; t2 < NT; ++t2) {
        commitK(t2 & 1);
        __syncthreads();
        if (t2 + 1 < NT) gloadK((t2 + 1) * TK);
        f32x16 c0; scores(t2 & 1, c0);
        float mk = mfl[t2 & 1][32 * c + m];
        #pragma unroll
        for (int r = 0; r < 16; ++r)
            if (mk == 0.f) rs[r] += __expf(c0[r] * SCALE);
    }
    #pragma unroll
    for (int off = 1; off < 32; off <<= 1)
        #pragma unroll
        for (int r = 0; r < 16; ++r) rs[r] += __shfl_xor(rs[r], off, 64);
    if (m == 0) {
        #pragma unroll
        for (int r = 0; r < 16; ++r) rsum[c][32 * p + rowof(h, r)] = rs[r];
    }
    __syncthreads();
    float rli[16];
    #pragma unroll
    for (int r = 0; r < 16; ++r) {
        int row = 32 * p + rowof(h, r);
        float tot = rsum[0][row] + rsum[1][row];
        rli[r] = tot > 0.f ? 1.f / tot : 0.f;
    }

    // ---------------- pass 2: attn write + PV ----------------
    f32x16 o;
    #pragma unroll
    for (int i = 0; i < 16; ++i) o[i] = 0.f;

    gloadK(0); gloadV(0);
    for (int t2 = 0; t2 < NT; ++t2) {
        const int gk = t2 * TK;
        const int buf = t2 & 1;
        commitK(buf); commitV(buf);
        __syncthreads();                               // A: staging visible; prev Ps fully consumed
        if (t2 + 1 < NT) { gloadK(gk + TK); gloadV(gk + TK); }

        f32x16 c0; scores(buf, c0);
        float mk = mfl[buf][32 * c + m];
        #pragma unroll
        for (int r = 0; r < 16; ++r) {
            float pv = (mk == 0.f) ? __expf(c0[r] * SCALE) * rli[r] : 0.f;
            Ps[(32 * p + rowof(h, r)) * STRH + 32 * c + m] = (short)f2bf(pv);
        }
        __syncthreads();                               // B: Ps complete

        // attn store: 64 rows x 64 cols, per thread 2 chunks of 8 cols (b128 LDS read, 2x16B global)
        float* ab = attng + ((size_t)(b * S + q0)) * S + gk;
        #pragma unroll
        for (int i = 0; i < 2; ++i) {
            int ch = t + 256 * i;
            int rr = ch >> 3, o8 = ch & 7;
            bf16x8 pv8 = *(const bf16x8*)&Ps[rr * STRH + o8 * 8];
            float4 f0 = make_float4(bf2f(pv8[0]), bf2f(pv8[1]), bf2f(pv8[2]), bf2f(pv8[3]));
            float4 f1 = make_float4(bf2f(pv8[4]), bf2f(pv8[5]), bf2f(pv8[6]), bf2f(pv8[7]));
            float* dst = ab + (size_t)rr * S + o8 * 8;
            *(float4*)dst = f0; *(float4*)(dst + 4) = f1;
        }
        // PV MFMA: A = P rows (32p+m), B = Vt rows (d = 32c+m)
        __builtin_amdgcn_s_setprio(1);
        #pragma unroll
        for (int kk = 0; kk < 4; ++kk) {
            bf16x8 ap = *(const bf16x8*)&Ps[(32 * p + m) * STRH + kk * 16 + h * 8];
            bf16x8 bv = *(const bf16x8*)&Vt[buf][(32 * c + m) * STRH + kk * 16 + h * 8];
            o = __builtin_amdgcn_mfma_f32_32x32x16_bf16(ap, bv, o, 0, 0, 0);
        }
        __builtin_amdgcn_s_setprio(0);
    }

    // out: rows 32p+rowof, cols 32c+m
    #pragma unroll
    for (int r = 0; r < 16; ++r)
        outg[((size_t)(b * S + q0 + 32 * p + rowof(h, r))) * D + 32 * c + m] = o[r];
}

// ============ fallback (R2 kernel) if workspace is too small ============
__global__ __launch_bounds__(256)
void sdpa_fb(const float* __restrict__ qg, const float* __restrict__ kg,
             const float* __restrict__ vg, const int* __restrict__ maskg,
             float* __restrict__ outg, float* __restrict__ attng)
{
    constexpr int FSTR = 72;
    __shared__ __align__(16) short Qs[128 * FSTR];
    __shared__ __align__(16) short KsF[64 * FSTR];
    __shared__ __align__(16) short VtF[64 * FSTR];
    __shared__ __align__(16) short PsF[4 * 32 * FSTR];
    __shared__ float mflag[64];

    const int t = threadIdx.x;
    const int w = t >> 6, lane = t & 63, m = lane & 31, half = lane >> 5;
    const int b = blockIdx.x >> 4;
    const int q0 = (blockIdx.x & 15) * 128;

    {
        const float4* src = (const float4*)(qg + ((size_t)b * S + q0) * D);
        #pragma unroll
        for (int i = 0; i < 8; ++i) {
            int f4 = t + i * 256;
            float4 v = src[f4];
            unsigned* dst = (unsigned*)&Qs[(f4 >> 4) * FSTR + (f4 & 15) * 4];
            dst[0] = pk2(v.x, v.y); dst[1] = pk2(v.z, v.w);
        }
    }
    __syncthreads();
    bf16x8 aq[4];
    #pragma unroll
    for (int s = 0; s < 4; ++s)
        aq[s] = *(const bf16x8*)&Qs[(w * 32 + m) * FSTR + s * 16 + half * 8];

    auto stageK = [&](int gk) {
        const float4* src = (const float4*)(kg + ((size_t)b * S + gk) * D);
        #pragma unroll
        for (int i = 0; i < 4; ++i) {
            int f4 = t + i * 256;
            float4 v = src[f4];
            unsigned* dst = (unsigned*)&KsF[(f4 >> 4) * FSTR + (f4 & 15) * 4];
            dst[0] = pk2(v.x, v.y); dst[1] = pk2(v.z, v.w);
        }
        if (t < 64) mflag[t] = maskg[b * S + gk + t] ? 1.0f : 0.0f;
    };
    auto stageV = [&](int gk) {
        const float4* src = (const float4*)(vg + ((size_t)b * S + gk) * D);
        #pragma unroll
        for (int i = 0; i < 4; ++i) {
            int f4 = t + i * 256;
            float4 v = src[f4];
            int r = f4 >> 4, cc = (f4 & 15) * 4;
            VtF[(cc + 0) * FSTR + r] = (short)f2bf(v.x);
            VtF[(cc + 1) * FSTR + r] = (short)f2bf(v.y);
            VtF[(cc + 2) * FSTR + r] = (short)f2bf(v.z);
            VtF[(cc + 3) * FSTR + r] = (short)f2bf(v.w);
        }
    };
    auto scoresF = [&](f32x16& c0, f32x16& c1) {
        #pragma unroll
        for (int i = 0; i < 16; ++i) { c0[i] = 0.f; c1[i] = 0.f; }
        #pragma unroll
        for (int s = 0; s < 4; ++s) {
            bf16x8 b0 = *(const bf16x8*)&KsF[m * FSTR + s * 16 + half * 8];
            bf16x8 b1 = *(const bf16x8*)&KsF[(32 + m) * FSTR + s * 16 + half * 8];
            c0 = __builtin_amdgcn_mfma_f32_32x32x16_bf16(aq[s], b0, c0, 0, 0, 0);
            c1 = __builtin_amdgcn_mfma_f32_32x32x16_bf16(aq[s], b1, c1, 0, 0, 0);
        }
    };

    float rs[16];
    #pragma unroll
    for (int r = 0; r < 16; ++r) rs[r] = 0.f;
    for (int tile = 0; tile < NT; ++tile) {
        stageK(tile * TK);
        __syncthreads();
        f32x16 c0, c1; scoresF(c0, c1);
        float mk0 = mflag[m], mk1 = mflag[32 + m];
        #pragma unroll
        for (int r = 0; r < 16; ++r) {
            float p0 = (mk0 == 0.f) ? __expf(c0[r] * SCALE) : 0.f;
            float p1 = (mk1 == 0.f) ? __expf(c1[r] * SCALE) : 0.f;
            rs[r] += p0 + p1;
        }
        __syncthreads();
    }
    #pragma unroll
    for (int off = 1; off < 32; off <<= 1)
        #pragma unroll
        for (int r = 0; r < 16; ++r) rs[r] += __shfl_xor(rs[r], off, 64);
    float rli[16];
    #pragma unroll
    for (int r = 0; r < 16; ++r) rli[r] = rs[r] > 0.f ? 1.f / rs[r] : 0.f;

    f32x16 o0, o1;
    #pragma unroll
    for (int i = 0; i < 16; ++i) { o0[i] = 0.f; o1[i] = 0.f; }
    short* Pw = &PsF[w * 32 * FSTR];
    float* abase = attng + ((size_t)(b * S + q0 + w * 32)) * S;

    for (int tile = 0; tile < NT; ++tile) {
        const int gk = tile * TK;
        stageK(gk); stageV(gk);
        __syncthreads();
        f32x16 c0, c1; scoresF(c0, c1);
        float mk0 = mflag[m], mk1 = mflag[32 + m];
        #pragma unroll
        for (int r = 0; r < 16; ++r) {
            int row = rowof(half, r);
            float p0 = (mk0 == 0.f) ? __expf(c0[r] * SCALE) * rli[r] : 0.f;
            float p1 = (mk1 == 0.f) ? __expf(c1[r] * SCALE) * rli[r] : 0.f;
            Pw[row * FSTR + m]      = (short)f2bf(p0);
            Pw[row * FSTR + 32 + m] = (short)f2bf(p1);
        }
        #pragma unroll
        for (int i = 0; i < 16; ++i) {
            int row = i * 2 + half;
            unsigned u = *(const unsigned*)&Pw[row * FSTR + 2 * m];
            float2 val = make_float2(bf2f((unsigned short)(u & 0xffff)),
                                     bf2f((unsigned short)(u >> 16)));
            *(float2*)&abase[(size_t)row * S + gk + 2 * m] = val;
        }
        #pragma unroll
        for (int kk = 0; kk < 4; ++kk) {
            bf16x8 ap  = *(const bf16x8*)&Pw[m * FSTR + kk * 16 + half * 8];
            bf16x8 bv0 = *(const bf16x8*)&VtF[m * FSTR + kk * 16 + half * 8];
            bf16x8 bv1 = *(const bf16x8*)&VtF[(32 + m) * FSTR + kk * 16 + half * 8];
            o0 = __builtin_amdgcn_mfma_f32_32x32x16_bf16(ap, bv0, o0, 0, 0, 0);
            o1 = __builtin_amdgcn_mfma_f32_32x32x16_bf16(ap, bv1, o1, 0, 0, 0);
        }
        __syncthreads();
    }
    float* obase = outg + ((size_t)(b * S + q0 + w * 32)) * D;
    #pragma unroll
    for (int r = 0; r < 16; ++r) {
        int row = rowof(half, r);
        obase[row * D + m]      = o0[r];
        obase[row * D + 32 + m] = o1[r];
    }
}

extern "C" void kernel_launch(void* const* d_in, const int* in_sizes, int n_in,
                              void* d_out, int out_size, void* d_ws, size_t ws_size,
                              hipStream_t stream) {
    const float* q    = (const float*)d_in[0];
    const float* k    = (const float*)d_in[1];
    const float* v    = (const float*)d_in[2];
    const int*   mask = (const int*)d_in[3];

    float* out  = (float*)d_out;
    float* attn = (float*)d_out + (size_t)B * S * D;

    const size_t elems = (size_t)B * S * D;
    const size_t need  = 3 * elems * sizeof(unsigned short);

    if (ws_size >= need) {
        unsigned short* Qb  = (unsigned short*)d_ws;
        unsigned short* Kb  = Qb + elems;
        unsigned short* Vtb = Kb + elems;
        preconv<<<dim3(B * (S / 64)), dim3(256), 0, stream>>>(q, k, v, Qb, Kb, Vtb);
        sdpa_v5<<<dim3(B * (S / 64)), dim3(256), 0, stream>>>(Qb, Kb, Vtb, mask, out, attn);
    } else {
        sdpa_fb<<<dim3(B * (S / 128)), dim3(256), 0, stream>>>(q, k, v, mask, out, attn);
    }
}